// Round 8
// baseline (436.307 us; speedup 1.0000x reference)
//
#include <hip/hip_runtime.h>
#include <hip/hip_bf16.h>
#include <stdint.h>

// ---------------------------------------------------------------------------
// fp32 inputs; mask int32; fp32 output. Internal pipeline bf16/f16.
// LayerNorm -> fused {q,kv} proj GEMMs with l2norm epilogues (V emitted f16)
//   -> flash attn: S^T = K.Q^T (16x16x32 bf16) with PERMUTED K-token rows so
//      exp(S^T) packs straight into the A-operand of 16x16x32 f16 PV MFMAs;
//      mask applied as 0/-512 bias in the QK C-initializer -> out proj.
// R8: value-constructed vector assembly (no type-punned partial stores into
//     locals -> no alloca/scratch spill; R7's 300MB scratch traffic bug).
// ---------------------------------------------------------------------------

using f32x4  = __attribute__((ext_vector_type(4))) float;
using bf16x8 = __attribute__((ext_vector_type(8))) __bf16;
using f16x8  = __attribute__((ext_vector_type(8))) _Float16;
using uintv4 = __attribute__((ext_vector_type(4))) unsigned int;

__device__ __forceinline__ float b2f(unsigned short u) {
    return __uint_as_float(((unsigned)u) << 16);
}
__device__ __forceinline__ unsigned short f2b(float f) {
    unsigned u = __float_as_uint(f);
    u += 0x7fffu + ((u >> 16) & 1u);   // RNE
    return (unsigned short)(u >> 16);
}
__device__ __forceinline__ f32x4 mfma16(bf16x8 a, bf16x8 b, f32x4 c) {
    return __builtin_amdgcn_mfma_f32_16x16x32_bf16(a, b, c, 0, 0, 0);
}
__device__ __forceinline__ f32x4 mfma16h(f16x8 a, f16x8 b, f32x4 c) {
    return __builtin_amdgcn_mfma_f32_16x16x32_f16(a, b, c, 0, 0, 0);
}
// packed f32x2 -> f16x2 (RTZ), returned as the raw 32-bit pattern
__device__ __forceinline__ unsigned pk16(float a, float b) {
    return __builtin_bit_cast(unsigned, __builtin_amdgcn_cvt_pkrtz(a, b));
}
// async global->LDS, 16B/lane; LDS dst = wave-uniform base + lane*16
__device__ __forceinline__ void gl_lds16(const unsigned short* g, __bf16* l) {
    __builtin_amdgcn_global_load_lds(
        (const __attribute__((address_space(1))) unsigned int*)g,
        (__attribute__((address_space(3))) unsigned int*)l, 16, 0, 0);
}

// ------------- weight transpose + fp32->bf16: in[R][C] -> out[C][R] --------
__global__ __launch_bounds__(256) void transpose_f2b(
    const float* __restrict__ in, unsigned short* __restrict__ out,
    int R, int C)
{
    __shared__ unsigned short t[32][33];
    int tx = threadIdx.x, ty = threadIdx.y;       // (32,8)
    int c = blockIdx.x * 32 + tx;
#pragma unroll
    for (int i = 0; i < 4; ++i) {
        int r = blockIdx.y * 32 + ty + i * 8;
        t[ty + i * 8][tx] = f2b(in[(size_t)r * C + c]);
    }
    __syncthreads();
    int r2 = blockIdx.y * 32 + tx;
#pragma unroll
    for (int i = 0; i < 4; ++i) {
        int c2 = blockIdx.x * 32 + ty + i * 8;
        out[(size_t)c2 * R + r2] = t[tx][ty + i * 8];
    }
}

// -------- LayerNorm: one row (1024 fp32) per block of 256 -> bf16 ----------
__global__ __launch_bounds__(256) void ln_kernel(
    const float* __restrict__ x, const float* __restrict__ gamma,
    unsigned short* __restrict__ xn)
{
    int row = blockIdx.x, tid = threadIdx.x;
    int wave = tid >> 6, lane = tid & 63;
    float4 raw = *(const float4*)(x + ((size_t)row << 10) + (tid << 2));
    float v[4] = { raw.x, raw.y, raw.z, raw.w };
    float s  = v[0] + v[1] + v[2] + v[3];
    float s2 = v[0]*v[0] + v[1]*v[1] + v[2]*v[2] + v[3]*v[3];
#pragma unroll
    for (int off = 1; off < 64; off <<= 1) {
        s  += __shfl_xor(s, off);
        s2 += __shfl_xor(s2, off);
    }
    __shared__ float ps[4], ps2[4], sh[2];
    if (lane == 0) { ps[wave] = s; ps2[wave] = s2; }
    __syncthreads();
    if (tid == 0) {
        float S  = ps[0] + ps[1] + ps[2] + ps[3];
        float S2 = ps2[0] + ps2[1] + ps2[2] + ps2[3];
        float mu  = S * (1.f / 1024.f);
        float var = S2 * (1.f / 1024.f) - mu * mu;
        sh[0] = mu; sh[1] = rsqrtf(var + 1e-5f);
    }
    __syncthreads();
    float mu = sh[0], rstd = sh[1];
    float4 g4 = *(const float4*)(gamma + (tid << 2));
    float g[4] = { g4.x, g4.y, g4.z, g4.w };
    unsigned short o[4];
#pragma unroll
    for (int i = 0; i < 4; ++i) o[i] = f2b((v[i] - mu) * rstd * g[i]);
    uint2 out;
    out.x = (unsigned)o[0] | ((unsigned)o[1] << 16);
    out.y = (unsigned)o[2] | ((unsigned)o[3] << 16);
    *(uint2*)(xn + ((size_t)row << 10) + (tid << 2)) = out;
}

// ---- GEMM C[M,N]=A[M,K]*Bt[N,K]^T, 128x128, gl_lds staging, fused epilog --
// MODE 0 (QNORM): per-head l2norm rows + q_scale*0.125*log2e, bf16 out
// MODE 1 (KV):    cols<1024: l2norm + k_scale, bf16; cols>=1024: raw f16
// MODE 2 (F32):   plain f32 store
template<int MODE>
__global__ __launch_bounds__(256, 2) void gemm_bt(
    const unsigned short* __restrict__ A, const unsigned short* __restrict__ Bt,
    void* __restrict__ Cout, const float* __restrict__ scale,
    int M, int N, int K)
{
    __shared__ __bf16 As[128 * 32];
    __shared__ __bf16 Bs[128 * 32];
    int tid = threadIdx.x, lane = tid & 63, wave = tid >> 6;
    int quad = lane >> 4, l15 = lane & 15;
    int m0 = blockIdx.y * 128, n0 = blockIdx.x * 128;
    int wm = (wave & 1) * 64, wn = (wave >> 1) * 64;
    f32x4 acc[4][4] = {};

    const int srow = wave * 32 + (lane >> 2);
    const int scol = (lane & 3) << 3;
    const unsigned short* gA = A  + (size_t)(m0 + srow) * K + scol;
    const unsigned short* gB = Bt + (size_t)(n0 + srow) * K + scol;
    __bf16* lA0 = &As[(wave * 32) * 32];
    __bf16* lA1 = &As[(wave * 32 + 16) * 32];
    __bf16* lB0 = &Bs[(wave * 32) * 32];
    __bf16* lB1 = &Bs[(wave * 32 + 16) * 32];
    const size_t rstep = (size_t)16 * K;

    for (int k0 = 0; k0 < K; k0 += 32) {
        gl_lds16(gA,         lA0);
        gl_lds16(gA + rstep, lA1);
        gl_lds16(gB,         lB0);
        gl_lds16(gB + rstep, lB1);
        gA += 32; gB += 32;
        __syncthreads();
        bf16x8 af[4], bfv[4];
#pragma unroll
        for (int i = 0; i < 4; ++i)
            af[i] = *(const bf16x8*)&As[(wm + i * 16 + l15) * 32 + quad * 8];
#pragma unroll
        for (int j = 0; j < 4; ++j)
            bfv[j] = *(const bf16x8*)&Bs[(wn + j * 16 + l15) * 32 + quad * 8];
#pragma unroll
        for (int i = 0; i < 4; ++i)
#pragma unroll
            for (int j = 0; j < 4; ++j)
                acc[i][j] = mfma16(af[i], bfv[j], acc[i][j]);
        __syncthreads();
    }

    if (MODE == 2) {
#pragma unroll
        for (int i = 0; i < 4; ++i)
#pragma unroll
            for (int j = 0; j < 4; ++j) {
                int row = m0 + wm + i * 16 + quad * 4;
                int col = n0 + wn + j * 16 + l15;
                size_t base = (size_t)row * N + col;
#pragma unroll
                for (int r = 0; r < 4; ++r)
                    ((float*)Cout)[base + (size_t)r * N] = acc[i][j][r];
            }
        return;
    }

    // wave's 64 cols (wn + j*16 + l15) = exactly one head; head-dim = j*16+l15
    const bool isv = (MODE == 1) && ((n0 + wn) >= 1024);
    float sc[4];
    if (!isv) {
#pragma unroll
        for (int j = 0; j < 4; ++j) {
            float s = scale[j * 16 + l15];
            sc[j] = (MODE == 0) ? s * (0.125f * 1.44269504088896f) : s;
        }
    }
#pragma unroll
    for (int i = 0; i < 4; ++i)
#pragma unroll
        for (int r = 0; r < 4; ++r) {
            float mul = 1.f;
            if (!isv) {
                float ss = 0.f;
#pragma unroll
                for (int j = 0; j < 4; ++j) ss += acc[i][j][r] * acc[i][j][r];
                ss += __shfl_xor(ss, 1); ss += __shfl_xor(ss, 2);
                ss += __shfl_xor(ss, 4); ss += __shfl_xor(ss, 8);
                mul = rsqrtf(ss + 1e-12f);
            }
            size_t rowbase = (size_t)(m0 + wm + i * 16 + quad * 4 + r) * N
                           + n0 + wn + l15;
#pragma unroll
            for (int j = 0; j < 4; ++j) {
                float v = acc[i][j][r];
                unsigned short w = isv
                    ? __builtin_bit_cast(unsigned short, (_Float16)v)
                    : f2b(v * mul * sc[j]);
                ((unsigned short*)Cout)[rowbase + j * 16] = w;
            }
        }
}

// ---------------- null kv: l2norm k + k_scale (bf16); v raw f16 ------------
__global__ __launch_bounds__(256) void nullkv_kernel(
    const float* __restrict__ null_kv, const float* __restrict__ k_scale,
    unsigned short* __restrict__ knull, unsigned short* __restrict__ vnull)
{
    int wave = threadIdx.x >> 6, lane = threadIdx.x & 63;
    int h = blockIdx.x * 4 + wave;
    int idx = (h << 6) + lane;
    float kvl = null_kv[idx];
    float ss = kvl * kvl;
#pragma unroll
    for (int off = 1; off < 64; off <<= 1) ss += __shfl_xor(ss, off);
    knull[idx] = f2b(kvl * rsqrtf(ss + 1e-12f) * k_scale[lane]);
    vnull[idx] = __builtin_bit_cast(unsigned short, (_Float16)null_kv[1024 + idx]);
}

// ---------------- attention: BM=128 (4 waves x 32 rows), BT=64 tokens ------
// K rows staged PERMUTED: LDS row r holds physical token T(r) so that the
// C-layouts of S^T tiles (2g,2g+1) form the A-operand of 16x16x32 f16 PV:
//   T(r) = 32*(r>>5) + 8*((r>>2)&3) + 4*((r>>4)&1) + (r&3)
//   => A k-slot (quad*8+j) holds physical token 32g + 8*quad + j. V stays
// physical-order; its fragment is 4 consecutive tokpairs (b64-aligned).
// Mask enters as 0/-512 bias via the QK C-initializer (exp2(-512)=0).
__global__ __launch_bounds__(256, 4) void attn_kernel(
    const unsigned short* __restrict__ qn,    // [B*2048,1024] l2norm*qs*log2e/8
    const unsigned short* __restrict__ kv,    // [B*2048,2048] k bf16 | v f16
    const unsigned short* __restrict__ knull, // [16*64] bf16
    const unsigned short* __restrict__ vnull, // [16*64] f16
    const int* __restrict__ mask,             // [B*2048]
    unsigned short* __restrict__ ao)          // [B*2048,1024]
{
    __shared__ __bf16 Kt[2][64 * 64];          // [row][8 granules XOR r&7]
    __shared__ unsigned int Vt32[64 * 34];     // f16 [d][tokpair], stride 34
    __shared__ __align__(16) float biasLds[64];

    const int tid = threadIdx.x, lane = tid & 63, wave = tid >> 6;
    const int quad = lane >> 4, l15 = lane & 15;
    const int bh = blockIdx.x;                 // (b,h): K/V sharers same XCD
    const int b = bh >> 4, h = bh & 15;
    const int mbase = blockIdx.y * 128 + wave * 32;
    const size_t rowoff = (size_t)b * 2048;

    bf16x8 qf[2][2];                           // B-operand fragments
#pragma unroll
    for (int rg = 0; rg < 2; ++rg)
#pragma unroll
        for (int ks = 0; ks < 2; ++ks)
            qf[rg][ks] = *(const bf16x8*)
                &qn[((rowoff + mbase + rg * 16 + l15) << 10) + (h << 6) + ks * 32 + quad * 8];

    // K staging: lane covers LDS row r = wave*16 + p*8 + (lane>>3); slot
    // w = lane&7 holds d-block w ^ (r&7); source token = jbase + T(r).
    const int t8  = lane >> 3;
    const int ksc = ((lane & 7) ^ t8) << 3;    // (r&7)==t8 since base%8==0

    uint2 va[2], vb[2]; float vmsk;

    auto kIssue = [&](int nt, int buf) {
#pragma unroll
        for (int p = 0; p < 2; ++p) {
            int r = wave * 16 + p * 8 + t8;
            int T = ((r >> 5) << 5) | (((r >> 2) & 3) << 3)
                  | (((r >> 4) & 1) << 2) | (r & 3);
            int j = (nt << 6) + T;
            int jr = j - 1; if (jr > 2047) jr = 2047;
            const unsigned short* src = (j == 0)
                ? knull + (h << 6) + ksc
                : kv + ((rowoff + (size_t)jr) << 11) + (h << 6) + ksc;
            gl_lds16(src, &Kt[buf][(wave * 16 + p * 8) * 64]);
        }
    };
    auto vPrefetch = [&](int nt) {
#pragma unroll
        for (int it = 0; it < 2; ++it) {
            int u = it * 256 + tid;
            int tp = u >> 4, d0 = (u & 15) << 2;
            int j0 = (nt << 6) + tp * 2;
            int jr0 = j0 - 1; if (jr0 > 2047) jr0 = 2047;
            int jr1 = j0;     if (jr1 > 2047) jr1 = 2047;
            const unsigned short* s0 = (j0 == 0)
                ? vnull + (h << 6) + d0
                : kv + ((rowoff + (size_t)jr0) << 11) + 1024 + (h << 6) + d0;
            const unsigned short* s1 =
                  kv + ((rowoff + (size_t)jr1) << 11) + 1024 + (h << 6) + d0;
            va[it] = *(const uint2*)s0;
            vb[it] = *(const uint2*)s1;
        }
        int j = (nt << 6) + tid;               // only tid<64 consumed
        float bv = -512.f;
        if (j == 0 || (j <= 2048 && mask[b * 2048 + j - 1] != 0)) bv = 0.f;
        vmsk = bv;
    };
    auto vCommit = [&]() {
#pragma unroll
        for (int it = 0; it < 2; ++it) {
            int u = it * 256 + tid;
            int tp = u >> 4, d0 = (u & 15) << 2;
            unsigned ax = va[it].x, ay = va[it].y;
            unsigned bx = vb[it].x, by = vb[it].y;
            Vt32[(d0 + 0) * 34 + tp] = (ax & 0xffffu) | (bx << 16);
            Vt32[(d0 + 1) * 34 + tp] = (ax >> 16)     | (bx & 0xffff0000u);
            Vt32[(d0 + 2) * 34 + tp] = (ay & 0xffffu) | (by << 16);
            Vt32[(d0 + 3) * 34 + tp] = (ay >> 16)     | (by & 0xffff0000u);
        }
        if (tid < 64) biasLds[tid] = vmsk;
    };

    f32x4 O[2][4] = {};
    float rs[2] = {0.f, 0.f};

    kIssue(0, 0);
    vPrefetch(0);

    for (int nt = 0; nt < 33; ++nt) {
        const int buf = nt & 1;
        __syncthreads();   // drains gl_lds(nt)+V regs; prev readers done
        vCommit();
        __syncthreads();   // Vt32/bias visible (lgkm-only: cheap)
        if (nt < 32) {     // issue AFTER barrier: overlaps compute below
            kIssue(nt + 1, buf ^ 1);
            vPrefetch(nt + 1);
        }

#pragma unroll
        for (int g = 0; g < 2; ++g) {
            bf16x8 kf[2][2];
#pragma unroll
            for (int t = 0; t < 2; ++t) {
                const __bf16* kb = &Kt[buf][((g * 2 + t) * 16 + l15) * 64];
                kf[t][0] = *(const bf16x8*)&kb[(quad ^ (l15 & 7)) << 3];
                kf[t][1] = *(const bf16x8*)&kb[((4 + quad) ^ (l15 & 7)) << 3];
            }
            f16x8 vf8[4];
#pragma unroll
            for (int dt = 0; dt < 4; ++dt) {
                int cu = (dt * 16 + l15) * 34 + (g << 4) + (quad << 2);
                uint2 lo = *(const uint2*)&Vt32[cu];
                uint2 hi = *(const uint2*)&Vt32[cu + 2];
                uintv4 rv = { lo.x, lo.y, hi.x, hi.y };   // value-built: no alloca
                vf8[dt] = __builtin_bit_cast(f16x8, rv);
            }
            float4 b0 = *(const float4*)&biasLds[(g << 5) + (quad << 3)];
            float4 b1 = *(const float4*)&biasLds[(g << 5) + (quad << 3) + 4];
#pragma unroll
            for (int rg = 0; rg < 2; ++rg) {
                f32x4 s0 = { b0.x, b0.y, b0.z, b0.w };
                f32x4 s1 = { b1.x, b1.y, b1.z, b1.w };
                s0 = mfma16(kf[0][0], qf[rg][0], s0);
                s0 = mfma16(kf[0][1], qf[rg][1], s0);
                s1 = mfma16(kf[1][0], qf[rg][0], s1);
                s1 = mfma16(kf[1][1], qf[rg][1], s1);
                float e0 = __builtin_amdgcn_exp2f(s0[0]);
                float e1 = __builtin_amdgcn_exp2f(s0[1]);
                float e2 = __builtin_amdgcn_exp2f(s0[2]);
                float e3 = __builtin_amdgcn_exp2f(s0[3]);
                float e4 = __builtin_amdgcn_exp2f(s1[0]);
                float e5 = __builtin_amdgcn_exp2f(s1[1]);
                float e6 = __builtin_amdgcn_exp2f(s1[2]);
                float e7 = __builtin_amdgcn_exp2f(s1[3]);
                rs[rg] += ((e0 + e1) + (e2 + e3)) + ((e4 + e5) + (e6 + e7));
                uintv4 pu = { pk16(e0, e1), pk16(e2, e3),
                              pk16(e4, e5), pk16(e6, e7) };
                f16x8 p = __builtin_bit_cast(f16x8, pu);
#pragma unroll
                for (int dt = 0; dt < 4; ++dt)
                    O[rg][dt] = mfma16h(p, vf8[dt], O[rg][dt]);
            }
        }
    }

    // rs: lane(quad,l15) holds partial for q=l15 -> sum across quads
#pragma unroll
    for (int rg = 0; rg < 2; ++rg) {
        rs[rg] += __shfl_xor(rs[rg], 16);
        rs[rg] += __shfl_xor(rs[rg], 32);
    }
#pragma unroll
    for (int rg = 0; rg < 2; ++rg) {
        float inv[4];
#pragma unroll
        for (int r = 0; r < 4; ++r)
            inv[r] = 1.f / __shfl(rs[rg], quad * 4 + r);   // q = rg*16+quad*4+r
#pragma unroll
        for (int dt = 0; dt < 4; ++dt) {
            size_t base = ((rowoff + mbase + rg * 16 + quad * 4) << 10)
                        + (h << 6) + dt * 16 + l15;
#pragma unroll
            for (int r = 0; r < 4; ++r)
                ao[base + ((size_t)r << 10)] = f2b(O[rg][dt][r] * inv[r]);
        }
    }
}

// ---------------------------------------------------------------------------
extern "C" void kernel_launch(void* const* d_in, const int* in_sizes, int n_in,
                              void* d_out, int out_size, void* d_ws, size_t ws_size,
                              hipStream_t stream)
{
    const float* x       = (const float*)d_in[0];
    const int*   mask    = (const int*)d_in[1];
    const float* gamma   = (const float*)d_in[2];
    const float* null_kv = (const float*)d_in[3];
    const float* Wq      = (const float*)d_in[4];
    const float* Wkv     = (const float*)d_in[5];
    const float* q_scale = (const float*)d_in[6];
    const float* k_scale = (const float*)d_in[7];
    const float* Wout    = (const float*)d_in[8];

    // Workspace map (72.01 MB; ao aliases xn which is dead after the GEMMs)
    char* ws = (char*)d_ws;
    unsigned short* xn    = (unsigned short*)(ws);                 // 16 MB
    unsigned short* ao    = xn;                                    // reuse
    unsigned short* q     = (unsigned short*)(ws + (16u << 20));   // 16 MB
    unsigned short* kvb   = (unsigned short*)(ws + (32u << 20));   // 32 MB
    unsigned short* WqT   = (unsigned short*)(ws + (64u << 20));   // 2 MB
    unsigned short* WkvT  = (unsigned short*)(ws + (66u << 20));   // 4 MB
    unsigned short* WoutT = (unsigned short*)(ws + (70u << 20));   // 2 MB
    unsigned short* knull = (unsigned short*)(ws + (72u << 20));   // 2 KB
    unsigned short* vnull = (unsigned short*)(ws + (72u << 20) + 4096);

    dim3 tb(32, 8);
    transpose_f2b<<<dim3(32, 32), tb, 0, stream>>>(Wq,   WqT,   1024, 1024);
    transpose_f2b<<<dim3(64, 32), tb, 0, stream>>>(Wkv,  WkvT,  1024, 2048);
    transpose_f2b<<<dim3(32, 32), tb, 0, stream>>>(Wout, WoutT, 1024, 1024);

    ln_kernel<<<8192, 256, 0, stream>>>(x, gamma, xn);

    gemm_bt<0><<<dim3(8, 64),  256, 0, stream>>>(xn, WqT,  q,   q_scale, 8192, 1024, 1024);
    gemm_bt<1><<<dim3(16, 64), 256, 0, stream>>>(xn, WkvT, kvb, k_scale, 8192, 2048, 1024);

    nullkv_kernel<<<4, 256, 0, stream>>>(null_kv, k_scale, knull, vnull);

    attn_kernel<<<dim3(64, 16), 256, 0, stream>>>(q, kvb, knull, vnull, mask, ao);

    gemm_bt<2><<<dim3(8, 64), 256, 0, stream>>>(ao, WoutT, d_out, nullptr,
                                                8192, 1024, 1024);
}

// Round 9
// 314.557 us; speedup vs baseline: 1.3870x; 1.3870x over previous
//
#include <hip/hip_runtime.h>
#include <hip/hip_bf16.h>
#include <stdint.h>

// ---------------------------------------------------------------------------
// fp32 inputs; mask int32; fp32 output. Internal pipeline bf16/f16.
// LayerNorm -> fused {q,kv} proj GEMMs with l2norm epilogues (V emitted f16)
//   -> flash attn: S^T = K.Q^T (16x16x32 bf16) with PERMUTED K-token rows so
//      exp(S^T) packs straight into the A-operand of 16x16x32 f16 PV MFMAs;
//      mask applied as 0/-512 bias in the QK C-initializer -> out proj.
// R9: attn __launch_bounds__(256,3) — (256,4) capped unified VGPR+AGPR at
//     128/wave (64+64 observed), spilling ~32B/thread/iter = the 280+ MB
//     symmetric TCC traffic of R7/R8. Budget 170 removes all spills. Inner
//     loop restructured to cut peak liveness (one kf pair live at a time).
// ---------------------------------------------------------------------------

using f32x4  = __attribute__((ext_vector_type(4))) float;
using bf16x8 = __attribute__((ext_vector_type(8))) __bf16;
using f16x8  = __attribute__((ext_vector_type(8))) _Float16;
using uintv4 = __attribute__((ext_vector_type(4))) unsigned int;

__device__ __forceinline__ float b2f(unsigned short u) {
    return __uint_as_float(((unsigned)u) << 16);
}
__device__ __forceinline__ unsigned short f2b(float f) {
    unsigned u = __float_as_uint(f);
    u += 0x7fffu + ((u >> 16) & 1u);   // RNE
    return (unsigned short)(u >> 16);
}
__device__ __forceinline__ f32x4 mfma16(bf16x8 a, bf16x8 b, f32x4 c) {
    return __builtin_amdgcn_mfma_f32_16x16x32_bf16(a, b, c, 0, 0, 0);
}
__device__ __forceinline__ f32x4 mfma16h(f16x8 a, f16x8 b, f32x4 c) {
    return __builtin_amdgcn_mfma_f32_16x16x32_f16(a, b, c, 0, 0, 0);
}
// packed f32x2 -> f16x2 (RTZ), returned as the raw 32-bit pattern
__device__ __forceinline__ unsigned pk16(float a, float b) {
    return __builtin_bit_cast(unsigned, __builtin_amdgcn_cvt_pkrtz(a, b));
}
// async global->LDS, 16B/lane; LDS dst = wave-uniform base + lane*16
__device__ __forceinline__ void gl_lds16(const unsigned short* g, __bf16* l) {
    __builtin_amdgcn_global_load_lds(
        (const __attribute__((address_space(1))) unsigned int*)g,
        (__attribute__((address_space(3))) unsigned int*)l, 16, 0, 0);
}

// ------------- weight transpose + fp32->bf16: in[R][C] -> out[C][R] --------
__global__ __launch_bounds__(256) void transpose_f2b(
    const float* __restrict__ in, unsigned short* __restrict__ out,
    int R, int C)
{
    __shared__ unsigned short t[32][33];
    int tx = threadIdx.x, ty = threadIdx.y;       // (32,8)
    int c = blockIdx.x * 32 + tx;
#pragma unroll
    for (int i = 0; i < 4; ++i) {
        int r = blockIdx.y * 32 + ty + i * 8;
        t[ty + i * 8][tx] = f2b(in[(size_t)r * C + c]);
    }
    __syncthreads();
    int r2 = blockIdx.y * 32 + tx;
#pragma unroll
    for (int i = 0; i < 4; ++i) {
        int c2 = blockIdx.x * 32 + ty + i * 8;
        out[(size_t)c2 * R + r2] = t[tx][ty + i * 8];
    }
}

// -------- LayerNorm: one row (1024 fp32) per block of 256 -> bf16 ----------
__global__ __launch_bounds__(256) void ln_kernel(
    const float* __restrict__ x, const float* __restrict__ gamma,
    unsigned short* __restrict__ xn)
{
    int row = blockIdx.x, tid = threadIdx.x;
    int wave = tid >> 6, lane = tid & 63;
    float4 raw = *(const float4*)(x + ((size_t)row << 10) + (tid << 2));
    float v[4] = { raw.x, raw.y, raw.z, raw.w };
    float s  = v[0] + v[1] + v[2] + v[3];
    float s2 = v[0]*v[0] + v[1]*v[1] + v[2]*v[2] + v[3]*v[3];
#pragma unroll
    for (int off = 1; off < 64; off <<= 1) {
        s  += __shfl_xor(s, off);
        s2 += __shfl_xor(s2, off);
    }
    __shared__ float ps[4], ps2[4], sh[2];
    if (lane == 0) { ps[wave] = s; ps2[wave] = s2; }
    __syncthreads();
    if (tid == 0) {
        float S  = ps[0] + ps[1] + ps[2] + ps[3];
        float S2 = ps2[0] + ps2[1] + ps2[2] + ps2[3];
        float mu  = S * (1.f / 1024.f);
        float var = S2 * (1.f / 1024.f) - mu * mu;
        sh[0] = mu; sh[1] = rsqrtf(var + 1e-5f);
    }
    __syncthreads();
    float mu = sh[0], rstd = sh[1];
    float4 g4 = *(const float4*)(gamma + (tid << 2));
    float g[4] = { g4.x, g4.y, g4.z, g4.w };
    unsigned short o[4];
#pragma unroll
    for (int i = 0; i < 4; ++i) o[i] = f2b((v[i] - mu) * rstd * g[i]);
    uint2 out;
    out.x = (unsigned)o[0] | ((unsigned)o[1] << 16);
    out.y = (unsigned)o[2] | ((unsigned)o[3] << 16);
    *(uint2*)(xn + ((size_t)row << 10) + (tid << 2)) = out;
}

// ---- GEMM C[M,N]=A[M,K]*Bt[N,K]^T, 128x128, gl_lds staging, fused epilog --
// MODE 0 (QNORM): per-head l2norm rows + q_scale*0.125*log2e, bf16 out
// MODE 1 (KV):    cols<1024: l2norm + k_scale, bf16; cols>=1024: raw f16
// MODE 2 (F32):   plain f32 store
template<int MODE>
__global__ __launch_bounds__(256, 2) void gemm_bt(
    const unsigned short* __restrict__ A, const unsigned short* __restrict__ Bt,
    void* __restrict__ Cout, const float* __restrict__ scale,
    int M, int N, int K)
{
    __shared__ __bf16 As[128 * 32];
    __shared__ __bf16 Bs[128 * 32];
    int tid = threadIdx.x, lane = tid & 63, wave = tid >> 6;
    int quad = lane >> 4, l15 = lane & 15;
    int m0 = blockIdx.y * 128, n0 = blockIdx.x * 128;
    int wm = (wave & 1) * 64, wn = (wave >> 1) * 64;
    f32x4 acc[4][4] = {};

    const int srow = wave * 32 + (lane >> 2);
    const int scol = (lane & 3) << 3;
    const unsigned short* gA = A  + (size_t)(m0 + srow) * K + scol;
    const unsigned short* gB = Bt + (size_t)(n0 + srow) * K + scol;
    __bf16* lA0 = &As[(wave * 32) * 32];
    __bf16* lA1 = &As[(wave * 32 + 16) * 32];
    __bf16* lB0 = &Bs[(wave * 32) * 32];
    __bf16* lB1 = &Bs[(wave * 32 + 16) * 32];
    const size_t rstep = (size_t)16 * K;

    for (int k0 = 0; k0 < K; k0 += 32) {
        gl_lds16(gA,         lA0);
        gl_lds16(gA + rstep, lA1);
        gl_lds16(gB,         lB0);
        gl_lds16(gB + rstep, lB1);
        gA += 32; gB += 32;
        __syncthreads();
        bf16x8 af[4], bfv[4];
#pragma unroll
        for (int i = 0; i < 4; ++i)
            af[i] = *(const bf16x8*)&As[(wm + i * 16 + l15) * 32 + quad * 8];
#pragma unroll
        for (int j = 0; j < 4; ++j)
            bfv[j] = *(const bf16x8*)&Bs[(wn + j * 16 + l15) * 32 + quad * 8];
#pragma unroll
        for (int i = 0; i < 4; ++i)
#pragma unroll
            for (int j = 0; j < 4; ++j)
                acc[i][j] = mfma16(af[i], bfv[j], acc[i][j]);
        __syncthreads();
    }

    if (MODE == 2) {
#pragma unroll
        for (int i = 0; i < 4; ++i)
#pragma unroll
            for (int j = 0; j < 4; ++j) {
                int row = m0 + wm + i * 16 + quad * 4;
                int col = n0 + wn + j * 16 + l15;
                size_t base = (size_t)row * N + col;
#pragma unroll
                for (int r = 0; r < 4; ++r)
                    ((float*)Cout)[base + (size_t)r * N] = acc[i][j][r];
            }
        return;
    }

    // wave's 64 cols (wn + j*16 + l15) = exactly one head; head-dim = j*16+l15
    const bool isv = (MODE == 1) && ((n0 + wn) >= 1024);
    float sc[4];
    if (!isv) {
#pragma unroll
        for (int j = 0; j < 4; ++j) {
            float s = scale[j * 16 + l15];
            sc[j] = (MODE == 0) ? s * (0.125f * 1.44269504088896f) : s;
        }
    }
#pragma unroll
    for (int i = 0; i < 4; ++i)
#pragma unroll
        for (int r = 0; r < 4; ++r) {
            float mul = 1.f;
            if (!isv) {
                float ss = 0.f;
#pragma unroll
                for (int j = 0; j < 4; ++j) ss += acc[i][j][r] * acc[i][j][r];
                ss += __shfl_xor(ss, 1); ss += __shfl_xor(ss, 2);
                ss += __shfl_xor(ss, 4); ss += __shfl_xor(ss, 8);
                mul = rsqrtf(ss + 1e-12f);
            }
            size_t rowbase = (size_t)(m0 + wm + i * 16 + quad * 4 + r) * N
                           + n0 + wn + l15;
#pragma unroll
            for (int j = 0; j < 4; ++j) {
                float v = acc[i][j][r];
                unsigned short w = isv
                    ? __builtin_bit_cast(unsigned short, (_Float16)v)
                    : f2b(v * mul * sc[j]);
                ((unsigned short*)Cout)[rowbase + j * 16] = w;
            }
        }
}

// ---------------- null kv: l2norm k + k_scale (bf16); v raw f16 ------------
__global__ __launch_bounds__(256) void nullkv_kernel(
    const float* __restrict__ null_kv, const float* __restrict__ k_scale,
    unsigned short* __restrict__ knull, unsigned short* __restrict__ vnull)
{
    int wave = threadIdx.x >> 6, lane = threadIdx.x & 63;
    int h = blockIdx.x * 4 + wave;
    int idx = (h << 6) + lane;
    float kvl = null_kv[idx];
    float ss = kvl * kvl;
#pragma unroll
    for (int off = 1; off < 64; off <<= 1) ss += __shfl_xor(ss, off);
    knull[idx] = f2b(kvl * rsqrtf(ss + 1e-12f) * k_scale[lane]);
    vnull[idx] = __builtin_bit_cast(unsigned short, (_Float16)null_kv[1024 + idx]);
}

// ---------------- attention: BM=128 (4 waves x 32 rows), BT=64 tokens ------
// K rows staged PERMUTED: LDS row r holds physical token T(r) so that the
// C-layouts of S^T tiles (2g,2g+1) form the A-operand of 16x16x32 f16 PV:
//   T(r) = 32*(r>>5) + 8*((r>>2)&3) + 4*((r>>4)&1) + (r&3)
//   => A k-slot (quad*8+j) holds physical token 32g + 8*quad + j. V stays
// physical-order; its fragment is 4 consecutive tokpairs (b64-aligned).
// Mask enters as 0/-512 bias via the QK C-initializer (exp2(-512)=0).
// launch_bounds (256,3): 170-reg unified budget -> no spills (see R9 note).
__global__ __launch_bounds__(256, 3) void attn_kernel(
    const unsigned short* __restrict__ qn,    // [B*2048,1024] l2norm*qs*log2e/8
    const unsigned short* __restrict__ kv,    // [B*2048,2048] k bf16 | v f16
    const unsigned short* __restrict__ knull, // [16*64] bf16
    const unsigned short* __restrict__ vnull, // [16*64] f16
    const int* __restrict__ mask,             // [B*2048]
    unsigned short* __restrict__ ao)          // [B*2048,1024]
{
    __shared__ __bf16 Kt[2][64 * 64];          // [row][8 granules XOR r&7]
    __shared__ unsigned int Vt32[64 * 34];     // f16 [d][tokpair], stride 34
    __shared__ __align__(16) float biasLds[64];

    const int tid = threadIdx.x, lane = tid & 63, wave = tid >> 6;
    const int quad = lane >> 4, l15 = lane & 15;
    const int bh = blockIdx.x;                 // (b,h): K/V sharers same XCD
    const int b = bh >> 4, h = bh & 15;
    const int mbase = blockIdx.y * 128 + wave * 32;
    const size_t rowoff = (size_t)b * 2048;

    bf16x8 qf[2][2];                           // B-operand fragments
#pragma unroll
    for (int rg = 0; rg < 2; ++rg)
#pragma unroll
        for (int ks = 0; ks < 2; ++ks)
            qf[rg][ks] = *(const bf16x8*)
                &qn[((rowoff + mbase + rg * 16 + l15) << 10) + (h << 6) + ks * 32 + quad * 8];

    // K staging: lane covers LDS row r = wave*16 + p*8 + (lane>>3); slot
    // w = lane&7 holds d-block w ^ (r&7); source token = jbase + T(r).
    const int t8  = lane >> 3;
    const int ksc = ((lane & 7) ^ t8) << 3;    // (r&7)==t8 since base%8==0

    uint2 va[2], vb[2]; float vmsk;

    auto kIssue = [&](int nt, int buf) {
#pragma unroll
        for (int p = 0; p < 2; ++p) {
            int r = wave * 16 + p * 8 + t8;
            int T = ((r >> 5) << 5) | (((r >> 2) & 3) << 3)
                  | (((r >> 4) & 1) << 2) | (r & 3);
            int j = (nt << 6) + T;
            int jr = j - 1; if (jr > 2047) jr = 2047;
            const unsigned short* src = (j == 0)
                ? knull + (h << 6) + ksc
                : kv + ((rowoff + (size_t)jr) << 11) + (h << 6) + ksc;
            gl_lds16(src, &Kt[buf][(wave * 16 + p * 8) * 64]);
        }
    };
    auto vPrefetch = [&](int nt) {
#pragma unroll
        for (int it = 0; it < 2; ++it) {
            int u = it * 256 + tid;
            int tp = u >> 4, d0 = (u & 15) << 2;
            int j0 = (nt << 6) + tp * 2;
            int jr0 = j0 - 1; if (jr0 > 2047) jr0 = 2047;
            int jr1 = j0;     if (jr1 > 2047) jr1 = 2047;
            const unsigned short* s0 = (j0 == 0)
                ? vnull + (h << 6) + d0
                : kv + ((rowoff + (size_t)jr0) << 11) + 1024 + (h << 6) + d0;
            const unsigned short* s1 =
                  kv + ((rowoff + (size_t)jr1) << 11) + 1024 + (h << 6) + d0;
            va[it] = *(const uint2*)s0;
            vb[it] = *(const uint2*)s1;
        }
        int j = (nt << 6) + tid;               // only tid<64 consumed
        float bv = -512.f;
        if (j == 0 || (j <= 2048 && mask[b * 2048 + j - 1] != 0)) bv = 0.f;
        vmsk = bv;
    };
    auto vCommit = [&]() {
#pragma unroll
        for (int it = 0; it < 2; ++it) {
            int u = it * 256 + tid;
            int tp = u >> 4, d0 = (u & 15) << 2;
            unsigned ax = va[it].x, ay = va[it].y;
            unsigned bx = vb[it].x, by = vb[it].y;
            Vt32[(d0 + 0) * 34 + tp] = (ax & 0xffffu) | (bx << 16);
            Vt32[(d0 + 1) * 34 + tp] = (ax >> 16)     | (bx & 0xffff0000u);
            Vt32[(d0 + 2) * 34 + tp] = (ay & 0xffffu) | (by << 16);
            Vt32[(d0 + 3) * 34 + tp] = (ay >> 16)     | (by & 0xffff0000u);
        }
        if (tid < 64) biasLds[tid] = vmsk;
    };

    f32x4 O[2][4] = {};
    float rs[2] = {0.f, 0.f};

    kIssue(0, 0);
    vPrefetch(0);

    for (int nt = 0; nt < 33; ++nt) {
        const int buf = nt & 1;
        __syncthreads();   // drains gl_lds(nt)+V regs; prev readers done
        vCommit();
        __syncthreads();   // Vt32/bias visible (lgkm-only: cheap)
        if (nt < 32) {     // issue AFTER barrier: overlaps compute below
            kIssue(nt + 1, buf ^ 1);
            vPrefetch(nt + 1);
        }

#pragma unroll
        for (int g = 0; g < 2; ++g) {
            // --- QK^T: only one kf pair (8 VGPRs) live at a time ---
            float4 b0 = *(const float4*)&biasLds[(g << 5) + (quad << 3)];
            float4 b1 = *(const float4*)&biasLds[(g << 5) + (quad << 3) + 4];
            f32x4 s[2][2];
#pragma unroll
            for (int rg = 0; rg < 2; ++rg) {
                s[rg][0] = f32x4{ b0.x, b0.y, b0.z, b0.w };
                s[rg][1] = f32x4{ b1.x, b1.y, b1.z, b1.w };
            }
#pragma unroll
            for (int t = 0; t < 2; ++t) {
                const __bf16* kb = &Kt[buf][((g * 2 + t) * 16 + l15) * 64];
                bf16x8 k0 = *(const bf16x8*)&kb[(quad ^ (l15 & 7)) << 3];
                bf16x8 k1 = *(const bf16x8*)&kb[((4 + quad) ^ (l15 & 7)) << 3];
#pragma unroll
                for (int rg = 0; rg < 2; ++rg) {
                    s[rg][t] = mfma16(k0, qf[rg][0], s[rg][t]);
                    s[rg][t] = mfma16(k1, qf[rg][1], s[rg][t]);
                }
            }
            // --- V fragments (loaded only after QK, before PV) ---
            f16x8 vf8[4];
#pragma unroll
            for (int dt = 0; dt < 4; ++dt) {
                int cu = (dt * 16 + l15) * 34 + (g << 4) + (quad << 2);
                uint2 lo = *(const uint2*)&Vt32[cu];
                uint2 hi = *(const uint2*)&Vt32[cu + 2];
                uintv4 rv = { lo.x, lo.y, hi.x, hi.y };
                vf8[dt] = __builtin_bit_cast(f16x8, rv);
            }
            // --- exp2 + pack + PV ---
#pragma unroll
            for (int rg = 0; rg < 2; ++rg) {
                float e0 = __builtin_amdgcn_exp2f(s[rg][0][0]);
                float e1 = __builtin_amdgcn_exp2f(s[rg][0][1]);
                float e2 = __builtin_amdgcn_exp2f(s[rg][0][2]);
                float e3 = __builtin_amdgcn_exp2f(s[rg][0][3]);
                float e4 = __builtin_amdgcn_exp2f(s[rg][1][0]);
                float e5 = __builtin_amdgcn_exp2f(s[rg][1][1]);
                float e6 = __builtin_amdgcn_exp2f(s[rg][1][2]);
                float e7 = __builtin_amdgcn_exp2f(s[rg][1][3]);
                rs[rg] += ((e0 + e1) + (e2 + e3)) + ((e4 + e5) + (e6 + e7));
                uintv4 pu = { pk16(e0, e1), pk16(e2, e3),
                              pk16(e4, e5), pk16(e6, e7) };
                f16x8 p = __builtin_bit_cast(f16x8, pu);
#pragma unroll
                for (int dt = 0; dt < 4; ++dt)
                    O[rg][dt] = mfma16h(p, vf8[dt], O[rg][dt]);
            }
        }
    }

    // rs: lane(quad,l15) holds partial for q=l15 -> sum across quads
#pragma unroll
    for (int rg = 0; rg < 2; ++rg) {
        rs[rg] += __shfl_xor(rs[rg], 16);
        rs[rg] += __shfl_xor(rs[rg], 32);
    }
#pragma unroll
    for (int rg = 0; rg < 2; ++rg) {
        float inv[4];
#pragma unroll
        for (int r = 0; r < 4; ++r)
            inv[r] = 1.f / __shfl(rs[rg], quad * 4 + r);   // q = rg*16+quad*4+r
#pragma unroll
        for (int dt = 0; dt < 4; ++dt) {
            size_t base = ((rowoff + mbase + rg * 16 + quad * 4) << 10)
                        + (h << 6) + dt * 16 + l15;
#pragma unroll
            for (int r = 0; r < 4; ++r)
                ao[base + ((size_t)r << 10)] = f2b(O[rg][dt][r] * inv[r]);
        }
    }
}

// ---------------------------------------------------------------------------
extern "C" void kernel_launch(void* const* d_in, const int* in_sizes, int n_in,
                              void* d_out, int out_size, void* d_ws, size_t ws_size,
                              hipStream_t stream)
{
    const float* x       = (const float*)d_in[0];
    const int*   mask    = (const int*)d_in[1];
    const float* gamma   = (const float*)d_in[2];
    const float* null_kv = (const float*)d_in[3];
    const float* Wq      = (const float*)d_in[4];
    const float* Wkv     = (const float*)d_in[5];
    const float* q_scale = (const float*)d_in[6];
    const float* k_scale = (const float*)d_in[7];
    const float* Wout    = (const float*)d_in[8];

    // Workspace map (72.01 MB; ao aliases xn which is dead after the GEMMs)
    char* ws = (char*)d_ws;
    unsigned short* xn    = (unsigned short*)(ws);                 // 16 MB
    unsigned short* ao    = xn;                                    // reuse
    unsigned short* q     = (unsigned short*)(ws + (16u << 20));   // 16 MB
    unsigned short* kvb   = (unsigned short*)(ws + (32u << 20));   // 32 MB
    unsigned short* WqT   = (unsigned short*)(ws + (64u << 20));   // 2 MB
    unsigned short* WkvT  = (unsigned short*)(ws + (66u << 20));   // 4 MB
    unsigned short* WoutT = (unsigned short*)(ws + (70u << 20));   // 2 MB
    unsigned short* knull = (unsigned short*)(ws + (72u << 20));   // 2 KB
    unsigned short* vnull = (unsigned short*)(ws + (72u << 20) + 4096);

    dim3 tb(32, 8);
    transpose_f2b<<<dim3(32, 32), tb, 0, stream>>>(Wq,   WqT,   1024, 1024);
    transpose_f2b<<<dim3(64, 32), tb, 0, stream>>>(Wkv,  WkvT,  1024, 2048);
    transpose_f2b<<<dim3(32, 32), tb, 0, stream>>>(Wout, WoutT, 1024, 1024);

    ln_kernel<<<8192, 256, 0, stream>>>(x, gamma, xn);

    gemm_bt<0><<<dim3(8, 64),  256, 0, stream>>>(xn, WqT,  q,   q_scale, 8192, 1024, 1024);
    gemm_bt<1><<<dim3(16, 64), 256, 0, stream>>>(xn, WkvT, kvb, k_scale, 8192, 2048, 1024);

    nullkv_kernel<<<4, 256, 0, stream>>>(null_kv, k_scale, knull, vnull);

    attn_kernel<<<dim3(64, 16), 256, 0, stream>>>(q, kvb, knull, vnull, mask, ao);

    gemm_bt<2><<<dim3(8, 64), 256, 0, stream>>>(ao, WoutT, d_out, nullptr,
                                                8192, 1024, 1024);
}